// Round 5
// baseline (311.298 us; speedup 1.0000x reference)
//
#include <hip/hip_runtime.h>
#include <hip/hip_bf16.h>

// B=64, L=512, H2=1536, T=64. logits = x@W + b -> softmax -> loss/acc.
// R5: barrier-free single-wave pipeline.
//   - bf16-split MFMA: x ~ xh+xl, W ~ wh+wl; x*W ~ xh*wh + xh*wl + xl*wh.
//   - 1 wave per block, NO __syncthreads in the K-loop. LDS/DMA ordering via
//     asm s_waitcnt vmcnt(24) + memory clobber (compiler can't reorder).
//   - Constant in-flight population per iter: issue B(s+1)[16] then DMA(s+2)[4];
//     vmcnt(24) drains exactly DMA(s)+B(s) (oldest 20), keeps DMA(s+1),
//     B(s+1), DMA(s+2) in flight across compute. 3 LDS buffers.
//   - Tail: clamped dummy prefetches keep counts constant (writes land in
//     unused slots / unused regs).

#define H2 1536
#define NT 64
#define ROWS (64 * 512)
#define KC 64                 // k per LDS buffer chunk
#define NITER (H2 / KC)       // 24
#define KS2 (H2 / 32)         // 48 MFMA k-steps
#define NBLK (ROWS / 16)      // 2048 blocks, 1 wave each

typedef __attribute__((ext_vector_type(8))) short short8;
typedef __attribute__((ext_vector_type(4))) float f32x4;

#define B_FRAGS (KS2 * 4 * 64)   // 12288 fragments x 16B (hi), same (lo)

__device__ __forceinline__ short bf_hi(float f) {
    __hip_bfloat16 h = __float2bfloat16(f);          // RNE
    return __builtin_bit_cast(short, h);
}
__device__ __forceinline__ float bf_f(short s) {
    __hip_bfloat16 h = __builtin_bit_cast(__hip_bfloat16, s);
    return __bfloat162float(h);
}

// Pack W[k][n] ([1536][64] k-major) into MFMA B-fragment order.
// Fragment (s2, c, lane): k = s2*32 + (lane>>4)*8 + j, n = c*16 + (lane&15).
__global__ void mlaner_prepw(const float* __restrict__ W,
                             short8* __restrict__ bhi, short8* __restrict__ blo)
{
    const int tid = blockIdx.x * 256 + threadIdx.x;   // 0..12287
    const int L = tid & 63, c = (tid >> 6) & 3, s2 = tid >> 8;
    const int kbase = s2 * 32 + (L >> 4) * 8;
    const int n = c * 16 + (L & 15);
    short8 hi, lo;
#pragma unroll
    for (int j = 0; j < 8; ++j) {
        float w = W[(size_t)(kbase + j) * NT + n];
        short h = bf_hi(w);
        hi[j] = h;
        lo[j] = bf_hi(w - bf_f(h));
    }
    const int idx = (s2 * 4 + c) * 64 + L;
    bhi[idx] = hi;
    blo[idx] = lo;
}

__device__ __forceinline__ void cvt_split(float4 a0, float4 a1,
                                          short8& hi, short8& lo)
{
    float v[8] = {a0.x, a0.y, a0.z, a0.w, a1.x, a1.y, a1.z, a1.w};
#pragma unroll
    for (int j = 0; j < 8; ++j) {
        short h = bf_hi(v[j]);
        hi[j] = h;
        lo[j] = bf_hi(v[j] - bf_f(h));
    }
}

__global__ __launch_bounds__(64, 2) void mlaner_main(
    const float* __restrict__ x,
    const short8* __restrict__ Bhi, const short8* __restrict__ Blo,
    const float* __restrict__ bias, const int* __restrict__ tags,
    const float* __restrict__ tag_to_score, const int* __restrict__ tptr,
    float* __restrict__ ploss, unsigned* __restrict__ pright,
    unsigned* __restrict__ pvalid)
{
    __shared__ float ldsbuf[3 * KC * 16];   // 3 x 4KB

    const int lane = threadIdx.x;
    const int blk = blockIdx.x;
    const int row0 = blk * 16;
    const int q = lane >> 4, n16 = lane & 15;

    // DMA one 4KB chunk (16 rows x 64 k) into LDS slot; 4 x 1KB issues.
    // LDS dest is wave-uniform base + lane*16 (HW rule). Global side applies
    // the bank swizzle: 16B slot j of row r holds global k-slot j^(r&7).
    auto dma = [&](int slot, int chunk) {
#pragma unroll
        for (int i = 0; i < 4; ++i) {
            const int idx = i * 64 + lane;          // 0..255 slot index
            const int r = idx >> 4, j = idx & 15;
            const int jg = j ^ (r & 7);
            const float* gp = x + (size_t)(row0 + r) * H2 + chunk * KC + jg * 4;
            __builtin_amdgcn_global_load_lds(
                (const __attribute__((address_space(1))) void*)gp,
                (__attribute__((address_space(3))) void*)&ldsbuf[slot * (KC * 16) + i * 256],
                16, 0, 0);
        }
    };

    auto load_B = [&](short8 (&bh)[2][4], short8 (&bl)[2][4], int s) {
#pragma unroll
        for (int h = 0; h < 2; ++h)
#pragma unroll
            for (int c = 0; c < 4; ++c) {
                const int f = ((s * 2 + h) * 4 + c) * 64 + lane;
                bh[h][c] = Bhi[f];
                bl[h][c] = Blo[f];
            }
    };

    f32x4 acc[4];
#pragma unroll
    for (int c = 0; c < 4; ++c) acc[c] = (f32x4){0.f, 0.f, 0.f, 0.f};

    short8 bhA[2][4], blA[2][4], bhB[2][4], blB[2][4];

    // Preamble: ages must be  B(0) < DMA(0) < DMA(1).
    load_B(bhA, blA, 0);
    dma(0, 0);
    dma(1, 1);

    // Body for iteration s: compute with (bhc,blc) = B(s) and LDS slot s%3,
    // after issuing B(s+1)->(bhn,bln) and DMA(s+2)->slot (s+2)%3.
    auto body = [&](short8 (&bhc)[2][4], short8 (&blc)[2][4],
                    short8 (&bhn)[2][4], short8 (&bln)[2][4], int s) {
        const int sb = (s + 1 < NITER) ? s + 1 : NITER - 1;   // clamp = dummy
        load_B(bhn, bln, sb);
        const int sd = (s + 2 < NITER) ? s + 2 : NITER - 1;   // clamp = dummy
        dma((s + 2) % 3, sd);

        // Drain to <=24 outstanding: completes DMA(s) (oldest) and B(s);
        // leaves DMA(s+1), B(s+1), DMA(s+2) in flight. Memory clobber keeps
        // the ds_reads below from moving above this point.
        asm volatile("s_waitcnt vmcnt(24)" ::: "memory");

        const float* bufp = &ldsbuf[(s % 3) * (KC * 16)];
#pragma unroll
        for (int h = 0; h < 2; ++h) {
            // A-fragment: lane(q,n16) = row n16, k = h*32 + q*8 + [0..8)
            const int sg0 = (h * 8 + 2 * q)     ^ (n16 & 7);
            const int sg1 = (h * 8 + 2 * q + 1) ^ (n16 & 7);
            float4 a0 = *(const float4*)&bufp[n16 * 64 + sg0 * 4];
            float4 a1 = *(const float4*)&bufp[n16 * 64 + sg1 * 4];
            short8 ah, al;
            cvt_split(a0, a1, ah, al);
#pragma unroll
            for (int c = 0; c < 4; ++c) {
                acc[c] = __builtin_amdgcn_mfma_f32_16x16x32_bf16(ah, bhc[h][c], acc[c], 0, 0, 0);
                acc[c] = __builtin_amdgcn_mfma_f32_16x16x32_bf16(ah, blc[h][c], acc[c], 0, 0, 0);
                acc[c] = __builtin_amdgcn_mfma_f32_16x16x32_bf16(al, bhc[h][c], acc[c], 0, 0, 0);
            }
        }
    };

#pragma unroll 1
    for (int it = 0; it < NITER / 2; ++it) {
        body(bhA, blA, bhB, blB, 2 * it);
        body(bhB, blB, bhA, blA, 2 * it + 1);
    }

    // ---- epilogue ----
    // C/D layout: col = c*16 + n16, row(local) = q*4 + i  [m89-verified]
    // attention_mask adds a row constant -> softmax/argmax invariant; skipped.
    const float bv0 = bias[n16], bv1 = bias[16 + n16];
    const float bv2 = bias[32 + n16], bv3 = bias[48 + n16];
    int tg[4];
#pragma unroll
    for (int i = 0; i < 4; ++i) tg[i] = tags[row0 + q * 4 + i];
    const int tt = tptr[0];
    const float e1c = expf(1.0f);
    float loss_acc = 0.0f;
    unsigned right_acc = 0, valid_acc = 0;

#pragma unroll 1
    for (int i = 0; i < 4; ++i) {
        float l0 = acc[0][i] + bv0, l1 = acc[1][i] + bv1;
        float l2 = acc[2][i] + bv2, l3 = acc[3][i] + bv3;

        float m = fmaxf(fmaxf(l0, l1), fmaxf(l2, l3));
#pragma unroll
        for (int off = 8; off >= 1; off >>= 1)
            m = fmaxf(m, __shfl_xor(m, off, 64));

        float e0 = expf(l0 - m), e1 = expf(l1 - m);
        float e2 = expf(l2 - m), e3 = expf(l3 - m);
        float Z = e0 + e1 + e2 + e3;
#pragma unroll
        for (int off = 8; off >= 1; off >>= 1)
            Z += __shfl_xor(Z, off, 64);

        float lp0 = logf(e0 / Z + 1e-10f), lp1 = logf(e1 / Z + 1e-10f);
        float lp2 = logf(e2 / Z + 1e-10f), lp3 = logf(e3 / Z + 1e-10f);
        float slp = lp0 + lp1 + lp2 + lp3;
#pragma unroll
        for (int off = 8; off >= 1; off >>= 1)
            slp += __shfl_xor(slp, off, 64);

        // argmax, numpy first-index tie semantics
        float bval = l0; int bcol = n16;
        if (l1 > bval) { bval = l1; bcol = 16 + n16; }
        if (l2 > bval) { bval = l2; bcol = 32 + n16; }
        if (l3 > bval) { bval = l3; bcol = 48 + n16; }
#pragma unroll
        for (int off = 8; off >= 1; off >>= 1) {
            float ov = __shfl_xor(bval, off, 64);
            int   oc = __shfl_xor(bcol, off, 64);
            if (ov > bval || (ov == bval && oc < bcol)) { bval = ov; bcol = oc; }
        }

        const int tag = tg[i];                 // uniform within 16-lane group
        const int csel = tag >> 4;
        float cand = (csel == 0) ? lp0 : (csel == 1) ? lp1 : (csel == 2) ? lp2 : lp3;
        float lptag = __shfl(cand, (lane & 48) | (tag & 15), 64);

        float sc = tag_to_score[tag];
        float sp = powf(sc, (float)tt);
        float es = expf(sp);
        float denom = 63.0f * e1c + es;
        float rowloss = -((e1c / denom) * (slp - lptag) + (es / denom) * lptag);

        if (n16 == 0) {
            loss_acc += rowloss;
            unsigned valid = (tag < NT - 3) ? 1u : 0u;
            valid_acc += valid;
            right_acc += (valid && bcol == tag) ? 1u : 0u;
        }
    }

#pragma unroll
    for (int off = 32; off >= 1; off >>= 1) {
        loss_acc += __shfl_xor(loss_acc, off, 64);
        right_acc += __shfl_xor((int)right_acc, off, 64);
        valid_acc += __shfl_xor((int)valid_acc, off, 64);
    }
    if (lane == 0) {
        ploss[blk] = loss_acc;
        pright[blk] = right_acc;
        pvalid[blk] = valid_acc;
    }
}

__global__ void mlaner_final(const float* __restrict__ pl,
                             const unsigned* __restrict__ pr,
                             const unsigned* __restrict__ pv,
                             float* __restrict__ out)
{
    __shared__ float sl[4];
    __shared__ unsigned sr[4], sv[4];
    const int tid = threadIdx.x, lane = tid & 63, wv = tid >> 6;
    float l = 0.0f; unsigned r = 0, v = 0;
    for (int i = tid; i < NBLK; i += 256) { l += pl[i]; r += pr[i]; v += pv[i]; }
#pragma unroll
    for (int off = 32; off >= 1; off >>= 1) {
        l += __shfl_xor(l, off, 64);
        r += __shfl_xor((int)r, off, 64);
        v += __shfl_xor((int)v, off, 64);
    }
    if (lane == 0) { sl[wv] = l; sr[wv] = r; sv[wv] = v; }
    __syncthreads();
    if (tid == 0) {
        float L = sl[0] + sl[1] + sl[2] + sl[3];
        unsigned R = sr[0] + sr[1] + sr[2] + sr[3];
        unsigned V = sv[0] + sv[1] + sv[2] + sv[3];
        out[0] = L;
        out[1] = (float)R / (float)V;
    }
}

extern "C" void kernel_launch(void* const* d_in, const int* in_sizes, int n_in,
                              void* d_out, int out_size, void* d_ws, size_t ws_size,
                              hipStream_t stream)
{
    const float* x    = (const float*)d_in[0];   // [64,512,1536] fp32
    const float* W    = (const float*)d_in[1];   // [1536,64] fp32
    const float* b    = (const float*)d_in[2];   // [64] fp32
    const int*   tags = (const int*)d_in[3];     // [64,512]
    // d_in[4]: attention_mask — softmax-shift-invariant, unused.
    const float* t2s  = (const float*)d_in[5];   // [64] fp32
    const int*   tptr = (const int*)d_in[6];     // scalar t
    float* out = (float*)d_out;                  // [loss1, acc1]

    // ws layout: Bhi | Blo | ploss[2048] | pright[2048] | pvalid[2048]
    short8* bhi = (short8*)d_ws;
    short8* blo = bhi + B_FRAGS;
    float* ploss = (float*)((char*)d_ws + (size_t)2 * B_FRAGS * 16);
    unsigned* pright = (unsigned*)(ploss + NBLK);
    unsigned* pvalid = pright + NBLK;
    // needs ws_size >= 393216 + 24576 bytes

    mlaner_prepw<<<dim3(B_FRAGS / 256), dim3(256), 0, stream>>>(W, bhi, blo);
    mlaner_main<<<dim3(NBLK), dim3(64), 0, stream>>>(
        x, bhi, blo, b, tags, t2s, tptr, ploss, pright, pvalid);
    mlaner_final<<<dim3(1), dim3(256), 0, stream>>>(ploss, pright, pvalid, out);
}